// Round 1
// baseline (2112.768 us; speedup 1.0000x reference)
//
#include <hip/hip_runtime.h>

#define TS 512      // seq len (B=1)
#define TD 3072     // llm dim
#define TDH 256     // history dim
#define TE 4        // experts
#define TF 8192     // ffn dim
#define TR 16       // lora rank
#define TH1 128     // fusion hidden

typedef unsigned short u16;
typedef unsigned int u32;

typedef short short8 __attribute__((ext_vector_type(8)));
typedef float f32x4 __attribute__((ext_vector_type(4)));

__device__ __forceinline__ u16 f2bf(float f) {
  union { float f; u32 u; } v; v.f = f;
  u32 r = v.u + 0x7fffu + ((v.u >> 16) & 1u);   // RNE
  return (u16)(r >> 16);
}
__device__ __forceinline__ u32 pk2(float a, float b) {
  return (u32)f2bf(a) | ((u32)f2bf(b) << 16);
}
__device__ __forceinline__ float bflo(u32 v) {
  union { u32 u; float f; } w; w.u = v << 16; return w.f;
}
__device__ __forceinline__ float bfhi(u32 v) {
  union { u32 u; float f; } w; w.u = v & 0xffff0000u; return w.f;
}
__device__ __forceinline__ float wred(float v) {
  #pragma unroll
  for (int o = 32; o; o >>= 1) v += __shfl_down(v, o);
  return v;
}
__device__ __forceinline__ float dot4(float4 a, float4 b) {
  return a.x*b.x + a.y*b.y + a.z*b.z + a.w*b.w;
}

// ---------------------------------------------------------------- zero out
__global__ void k_zero(float* __restrict__ p, int n) {
  for (int i = blockIdx.x * blockDim.x + threadIdx.x; i < n; i += gridDim.x * blockDim.x)
    p[i] = 0.f;
}

// ---------------------------------------------------------------- gating prep
// blocks 0..127: hb[k] = hist.fw1h[k] + fb1[k];  hp[e][k] = persona[e].fw1p[k]
// block 128:     sc[0] = sum ln_g*gate_w, sc[1] = sum ln_b*gate_w
__global__ void k_prep(const float* __restrict__ hist, const float* __restrict__ fw1h,
                       const float* __restrict__ fb1, const float* __restrict__ persona,
                       const float* __restrict__ fw1p, const float* __restrict__ lng,
                       const float* __restrict__ lnb, const float* __restrict__ gw,
                       float* __restrict__ hb, float* __restrict__ hp, float* __restrict__ sc)
{
  const int k = blockIdx.x, t = threadIdx.x;  // 64 threads
  if (k < TH1) {
    float a = 0.f;
    for (int h = t; h < TDH; h += 64) a += hist[h] * fw1h[k * TDH + h];
    a = wred(a);
    if (t == 0) hb[k] = a + fb1[k];
    for (int e = 0; e < TE; ++e) {
      float b = 0.f;
      for (int d = t; d < TD; d += 64) b += persona[e * TD + d] * fw1p[k * TD + d];
      b = wred(b);
      if (t == 0) hp[e * TH1 + k] = b;
    }
  } else {
    float g = 0.f, bb = 0.f;
    for (int d = t; d < TD; d += 64) { g += lng[d] * gw[d]; bb += lnb[d] * gw[d]; }
    g = wred(g); bb = wred(bb);
    if (t == 0) { sc[0] = g; sc[1] = bb; }
  }
}

// ---------------------------------------------------------------- h1 = x @ fw1x^T + hb
// grid 128 blocks x 128 threads, 4 seq rows per block
__global__ void k_h1(const float* __restrict__ x, const float* __restrict__ fw1x,
                     const float* __restrict__ hb, float* __restrict__ h1)
{
  const int s0 = blockIdx.x * 4, t = threadIdx.x;
  __shared__ float xr[4][TD];
  for (int r = 0; r < 4; ++r)
    for (int i = t; i < TD / 4; i += 128)
      ((float4*)xr[r])[i] = ((const float4*)(x + (size_t)(s0 + r) * TD))[i];
  __syncthreads();
  float a0 = 0.f, a1 = 0.f, a2 = 0.f, a3 = 0.f;
  const float4* wp = (const float4*)(fw1x + (size_t)t * TD);
  for (int c = 0; c < TD / 4; ++c) {
    float4 wv = wp[c];
    a0 += dot4(wv, ((const float4*)xr[0])[c]);
    a1 += dot4(wv, ((const float4*)xr[1])[c]);
    a2 += dot4(wv, ((const float4*)xr[2])[c]);
    a3 += dot4(wv, ((const float4*)xr[3])[c]);
  }
  const float hv = hb[t];
  h1[(s0 + 0) * TH1 + t] = a0 + hv;
  h1[(s0 + 1) * TH1 + t] = a1 + hv;
  h1[(s0 + 2) * TH1 + t] = a2 + hv;
  h1[(s0 + 3) * TH1 + t] = a3 + hv;
}

// ---------------------------------------------------------------- per-token expert logits
// fused = relu(relu(h1+hp[e]) @ fw2^T + fb2); logit = LN(fused).gate_w + gate_b
// computed via running sums (no fused materialization). grid S x 256 thr.
__global__ void k_logits(const float* __restrict__ h1, const float* __restrict__ hp,
                         const float* __restrict__ fw2, const float* __restrict__ fb2,
                         const float* __restrict__ lng, const float* __restrict__ lnb,
                         const float* __restrict__ gw, const float* __restrict__ gbp,
                         const float* __restrict__ sc, float* __restrict__ logits)
{
  const int s = blockIdx.x, t = threadIdx.x;
  __shared__ float h1e[TE][TH1];
  __shared__ float red[4][12];
  if (t < TH1) {
    const float base = h1[s * TH1 + t];
    #pragma unroll
    for (int e = 0; e < TE; ++e) {
      float v = base + hp[e * TH1 + t];
      h1e[e][t] = v > 0.f ? v : 0.f;
    }
  }
  __syncthreads();
  float acc[12][4];
  #pragma unroll
  for (int dd = 0; dd < 12; ++dd)
    #pragma unroll
    for (int e = 0; e < 4; ++e) acc[dd][e] = 0.f;

  for (int c = 0; c < 32; ++c) {
    float4 h4[TE];
    #pragma unroll
    for (int e = 0; e < TE; ++e) h4[e] = *(const float4*)&h1e[e][c * 4];
    #pragma unroll
    for (int dd = 0; dd < 12; ++dd) {
      const int d = t + dd * 256;
      float4 wv = *(const float4*)(fw2 + (size_t)d * TH1 + c * 4);
      #pragma unroll
      for (int e = 0; e < TE; ++e) acc[dd][e] += dot4(wv, h4[e]);
    }
  }
  float s1[4] = {0,0,0,0}, s2[4] = {0,0,0,0}, s3[4] = {0,0,0,0};
  #pragma unroll
  for (int dd = 0; dd < 12; ++dd) {
    const int d = t + dd * 256;
    const float fb = fb2[d];
    const float ggw = lng[d] * gw[d];
    #pragma unroll
    for (int e = 0; e < 4; ++e) {
      float f = acc[dd][e] + fb;
      f = fmaxf(f, 0.f);
      s1[e] += f; s2[e] += f * f; s3[e] += f * ggw;
    }
  }
  #pragma unroll
  for (int e = 0; e < 4; ++e) { s1[e] = wred(s1[e]); s2[e] = wred(s2[e]); s3[e] = wred(s3[e]); }
  const int lane = t & 63, w = t >> 6;
  if (lane == 0) {
    #pragma unroll
    for (int e = 0; e < 4; ++e) { red[w][e] = s1[e]; red[w][4 + e] = s2[e]; red[w][8 + e] = s3[e]; }
  }
  __syncthreads();
  if (t == 0) {
    const float dotg = sc[0], dotb = sc[1], gb = gbp[0];
    #pragma unroll
    for (int e = 0; e < 4; ++e) {
      float S1 = red[0][e] + red[1][e] + red[2][e] + red[3][e];
      float S2 = red[0][4+e] + red[1][4+e] + red[2][4+e] + red[3][4+e];
      float S3 = red[0][8+e] + red[1][8+e] + red[2][8+e] + red[3][8+e];
      float mu = S1 * (1.f / TD);
      float var = S2 * (1.f / TD) - mu * mu;
      float rs = 1.f / sqrtf(var + 1e-5f);
      logits[e * TS + s] = rs * (S3 - mu * dotg) + dotb + gb;
    }
  }
}

// ---------------------------------------------------------------- softmax/top2/entropy
__global__ void k_gate(const float* __restrict__ logits, float* __restrict__ wbuf,
                       float* __restrict__ entOut)
{
  const int s = threadIdx.x;  // 512 threads
  float l[4], p[4];
  #pragma unroll
  for (int e = 0; e < 4; ++e) l[e] = logits[e * TS + s];
  float m = fmaxf(fmaxf(l[0], l[1]), fmaxf(l[2], l[3]));
  float sum = 0.f;
  #pragma unroll
  for (int e = 0; e < 4; ++e) { p[e] = expf(l[e] - m); sum += p[e]; }
  const float inv = 1.f / sum;
  #pragma unroll
  for (int e = 0; e < 4; ++e) p[e] *= inv;
  int i1 = 0; float b1 = p[0];
  #pragma unroll
  for (int e = 1; e < 4; ++e) if (p[e] > b1) { b1 = p[e]; i1 = e; }
  int i2 = -1; float b2 = -1.f;
  #pragma unroll
  for (int e = 0; e < 4; ++e) if (e != i1 && p[e] > b2) { b2 = p[e]; i2 = e; }
  float ent = 0.f;
  #pragma unroll
  for (int e = 0; e < 4; ++e) {
    ent -= p[e] * logf(p[e] + 1e-9f);
    wbuf[s * TE + e] = (e == i1 || e == i2) ? p[e] : 0.f;
  }
  ent = wred(ent);
  __shared__ float red[8];
  if ((s & 63) == 0) red[s >> 6] = ent;
  __syncthreads();
  if (s == 0) {
    float tot = 0.f;
    #pragma unroll
    for (int w = 0; w < 8; ++w) tot += red[w];
    entOut[0] = tot * (1.f / TS);
  }
}

// ---------------------------------------------------------------- x -> bf16
__global__ void k_cvtx(const float* __restrict__ x, u16* __restrict__ xbf) {
  const size_t i = ((size_t)blockIdx.x * 256 + threadIdx.x) * 4;
  float4 v = *(const float4*)(x + i);
  uint2 o; o.x = pk2(v.x, v.y); o.y = pk2(v.z, v.w);
  *(uint2*)(xbf + i) = o;
}

// ---------------------------------------------------------------- xa = x @ A^T (gate & up), fp32 -> bf16
// grid (E, S) x 128 thr: wave0 -> Agate, wave1 -> Aup
__global__ void k_xa(const float* __restrict__ x, const float* __restrict__ Ag,
                     const float* __restrict__ Au, u16* __restrict__ xag, u16* __restrict__ xau)
{
  const int e = blockIdx.x, s = blockIdx.y, t = threadIdx.x;
  const int wavei = t >> 6, lane = t & 63;
  const int r = lane & 15, q = lane >> 4;
  const float* A = wavei ? Au : Ag;
  u16* dst = wavei ? xau : xag;
  const float4* xv = (const float4*)(x + (size_t)s * TD);
  const float4* av = (const float4*)(A + ((size_t)e * TR + r) * TD);
  float acc = 0.f;
  for (int c = q * 192; c < q * 192 + 192; ++c) acc += dot4(av[c], xv[c]);
  acc += __shfl_xor(acc, 16);
  acc += __shfl_xor(acc, 32);
  if (q == 0) dst[((size_t)e * TS + s) * TR + r] = f2bf(acc);
}

// ---------------------------------------------------------------- fused gate+up GEMM + LoRA + silu
// C = x @ W^T (+ xa @ B^T), 128x128 tiles, BK=32, bf16 MFMA, fp32 weights converted in staging.
// grid (F/128, S/128, E) x 256 thr
__global__ __launch_bounds__(256, 2) void k_gateup(
    const float* __restrict__ Wg, const float* __restrict__ Wu,
    const float* __restrict__ Bg, const float* __restrict__ Bu,
    const u16* __restrict__ xbf, const u16* __restrict__ xag,
    const u16* __restrict__ xau, u16* __restrict__ hbuf)
{
  __shared__ __attribute__((aligned(16))) u16 lA[128 * 40];
  __shared__ __attribute__((aligned(16))) u16 lBg[128 * 40];
  __shared__ __attribute__((aligned(16))) u16 lBu[128 * 40];
  __shared__ __attribute__((aligned(16))) u16 lA2[128 * 40];
  const int e = blockIdx.z;
  const int n0 = blockIdx.x * 128;
  const int m0 = blockIdx.y * 128;
  const int t = threadIdx.x;
  const int lane = t & 63, wv = t >> 6;
  const int wm = wv >> 1, wn = wv & 1;
  const int lr = lane & 15, lk = lane >> 4;

  f32x4 accg[4][4], accu[4][4];
  #pragma unroll
  for (int i = 0; i < 4; ++i)
    #pragma unroll
    for (int j = 0; j < 4; ++j) {
      f32x4 z = {0.f, 0.f, 0.f, 0.f};
      accg[i][j] = z; accu[i][j] = z;
    }

  const int r0 = t >> 2;          // 0..63 (row), +64 for second half
  const int cc0 = (t & 3) * 8;    // 8-elem chunk within BK=32
  const u16* Abase = xbf + (size_t)m0 * TD;
  const float* Gbase = Wg + ((size_t)e * TF + n0) * TD;
  const float* Ubase = Wu + ((size_t)e * TF + n0) * TD;

  for (int kt = 0; kt < TD; kt += 32) {
    #pragma unroll
    for (int h = 0; h < 2; ++h) {
      const int row = r0 + h * 64;
      *(uint4*)&lA[row * 40 + cc0] = *(const uint4*)(Abase + (size_t)row * TD + kt + cc0);
      const float4* gp = (const float4*)(Gbase + (size_t)row * TD + kt + cc0);
      float4 g0 = gp[0], g1 = gp[1];
      uint4 gpk; gpk.x = pk2(g0.x, g0.y); gpk.y = pk2(g0.z, g0.w);
      gpk.z = pk2(g1.x, g1.y); gpk.w = pk2(g1.z, g1.w);
      *(uint4*)&lBg[row * 40 + cc0] = gpk;
      const float4* up = (const float4*)(Ubase + (size_t)row * TD + kt + cc0);
      float4 u0 = up[0], u1 = up[1];
      uint4 upk; upk.x = pk2(u0.x, u0.y); upk.y = pk2(u0.z, u0.w);
      upk.z = pk2(u1.x, u1.y); upk.w = pk2(u1.z, u1.w);
      *(uint4*)&lBu[row * 40 + cc0] = upk;
    }
    __syncthreads();
    short8 af[4], bgf[4], buf[4];
    #pragma unroll
    for (int i = 0; i < 4; ++i) {
      af[i]  = *(const short8*)&lA [(wm * 64 + i * 16 + lr) * 40 + lk * 8];
      bgf[i] = *(const short8*)&lBg[(wn * 64 + i * 16 + lr) * 40 + lk * 8];
      buf[i] = *(const short8*)&lBu[(wn * 64 + i * 16 + lr) * 40 + lk * 8];
    }
    #pragma unroll
    for (int mi = 0; mi < 4; ++mi)
      #pragma unroll
      for (int ni = 0; ni < 4; ++ni) {
        accg[mi][ni] = __builtin_amdgcn_mfma_f32_16x16x32_bf16(af[mi], bgf[ni], accg[mi][ni], 0, 0, 0);
        accu[mi][ni] = __builtin_amdgcn_mfma_f32_16x16x32_bf16(af[mi], buf[ni], accu[mi][ni], 0, 0, 0);
      }
    __syncthreads();
  }

  // LoRA rank-16 extension step (K padded to 32 with zeros)
  for (int i = t; i < 4096; i += 256) {
    const int row = i >> 5, c = i & 31;
    u16 vag = 0, vau = 0, vbg = 0, vbu = 0;
    if (c < TR) {
      vag = xag[((size_t)e * TS + m0 + row) * TR + c];
      vau = xau[((size_t)e * TS + m0 + row) * TR + c];
      vbg = f2bf(Bg[((size_t)e * TF + n0 + row) * TR + c]);
      vbu = f2bf(Bu[((size_t)e * TF + n0 + row) * TR + c]);
    }
    lA [row * 40 + c] = vag;
    lA2[row * 40 + c] = vau;
    lBg[row * 40 + c] = vbg;
    lBu[row * 40 + c] = vbu;
  }
  __syncthreads();
  {
    short8 ag[4], au[4], bgf[4], buf[4];
    #pragma unroll
    for (int i = 0; i < 4; ++i) {
      ag[i]  = *(const short8*)&lA [(wm * 64 + i * 16 + lr) * 40 + lk * 8];
      au[i]  = *(const short8*)&lA2[(wm * 64 + i * 16 + lr) * 40 + lk * 8];
      bgf[i] = *(const short8*)&lBg[(wn * 64 + i * 16 + lr) * 40 + lk * 8];
      buf[i] = *(const short8*)&lBu[(wn * 64 + i * 16 + lr) * 40 + lk * 8];
    }
    #pragma unroll
    for (int mi = 0; mi < 4; ++mi)
      #pragma unroll
      for (int ni = 0; ni < 4; ++ni) {
        accg[mi][ni] = __builtin_amdgcn_mfma_f32_16x16x32_bf16(ag[mi], bgf[ni], accg[mi][ni], 0, 0, 0);
        accu[mi][ni] = __builtin_amdgcn_mfma_f32_16x16x32_bf16(au[mi], buf[ni], accu[mi][ni], 0, 0, 0);
      }
  }

  // epilogue: h = silu(g) * u -> bf16
  u16* hrow = hbuf + ((size_t)e * TS + m0) * TF + n0;
  #pragma unroll
  for (int mi = 0; mi < 4; ++mi)
    #pragma unroll
    for (int j = 0; j < 4; ++j) {
      const int srow = wm * 64 + mi * 16 + lk * 4 + j;
      #pragma unroll
      for (int ni = 0; ni < 4; ++ni) {
        const int fcol = wn * 64 + ni * 16 + lr;
        float g = accg[mi][ni][j];
        float u = accu[mi][ni][j];
        float hval = (g / (1.f + __expf(-g))) * u;
        hrow[(size_t)srow * TF + fcol] = f2bf(hval);
      }
    }
}

// ---------------------------------------------------------------- ha = h @ Adown^T (per expert), bf16 out
// grid (E, S) x 256 thr
__global__ void k_ha(const u16* __restrict__ hbuf, const float* __restrict__ Ad,
                     u16* __restrict__ ha)
{
  const int e = blockIdx.x, s = blockIdx.y, t = threadIdx.x;
  const int wv = t >> 6, lane = t & 63;
  const int r = lane & 15, seg = (lane >> 4) + (wv << 2);  // 0..15, 512 f each
  const u16* hrow = hbuf + ((size_t)e * TS + s) * TF + seg * 512;
  const float* arow = Ad + ((size_t)e * TR + r) * TF + seg * 512;
  float acc = 0.f;
  for (int i = 0; i < 512; i += 4) {
    uint2 hv = *(const uint2*)(hrow + i);
    float4 av = *(const float4*)(arow + i);
    acc += bflo(hv.x) * av.x + bfhi(hv.x) * av.y + bflo(hv.y) * av.z + bfhi(hv.y) * av.w;
  }
  acc += __shfl_xor(acc, 16);
  acc += __shfl_xor(acc, 32);
  __shared__ float red[4][16];
  if ((lane >> 4) == 0) red[wv][r] = acc;
  __syncthreads();
  if (wv == 0 && lane < 16) {
    float tot = red[0][lane] + red[1][lane] + red[2][lane] + red[3][lane];
    ha[((size_t)e * TS + s) * TR + lane] = f2bf(tot);
  }
}

// ---------------------------------------------------------------- down GEMM + LoRA + weighted combine
// grid (D/128, (S/128)*2 splitK, E) x 256 thr; atomic fp32 accumulate into out
__global__ __launch_bounds__(256, 3) void k_down(
    const float* __restrict__ Wd, const float* __restrict__ Bd,
    const u16* __restrict__ hbuf, const u16* __restrict__ ha,
    const float* __restrict__ wbuf, float* __restrict__ out)
{
  __shared__ __attribute__((aligned(16))) u16 lA[128 * 40];
  __shared__ __attribute__((aligned(16))) u16 lB[128 * 40];
  const int e = blockIdx.z;
  const int n0 = blockIdx.x * 128;                 // d offset
  const int m0 = (blockIdx.y >> 1) * 128;          // s offset
  const int kh = blockIdx.y & 1;                   // K half
  const int t = threadIdx.x;
  const int lane = t & 63, wv = t >> 6;
  const int wm = wv >> 1, wn = wv & 1;
  const int lr = lane & 15, lk = lane >> 4;

  f32x4 acc[4][4];
  #pragma unroll
  for (int i = 0; i < 4; ++i)
    #pragma unroll
    for (int j = 0; j < 4; ++j) { f32x4 z = {0.f, 0.f, 0.f, 0.f}; acc[i][j] = z; }

  const int r0 = t >> 2;
  const int cc0 = (t & 3) * 8;
  const u16* Abase = hbuf + ((size_t)e * TS + m0) * TF;
  const float* Bbase = Wd + ((size_t)e * TD + n0) * TF;

  const int k0 = kh * 4096;
  for (int kt = k0; kt < k0 + 4096; kt += 32) {
    #pragma unroll
    for (int h = 0; h < 2; ++h) {
      const int row = r0 + h * 64;
      *(uint4*)&lA[row * 40 + cc0] = *(const uint4*)(Abase + (size_t)row * TF + kt + cc0);
      const float4* p = (const float4*)(Bbase + (size_t)row * TF + kt + cc0);
      float4 v0 = p[0], v1 = p[1];
      uint4 pk; pk.x = pk2(v0.x, v0.y); pk.y = pk2(v0.z, v0.w);
      pk.z = pk2(v1.x, v1.y); pk.w = pk2(v1.z, v1.w);
      *(uint4*)&lB[row * 40 + cc0] = pk;
    }
    __syncthreads();
    short8 af[4], bf[4];
    #pragma unroll
    for (int i = 0; i < 4; ++i) {
      af[i] = *(const short8*)&lA[(wm * 64 + i * 16 + lr) * 40 + lk * 8];
      bf[i] = *(const short8*)&lB[(wn * 64 + i * 16 + lr) * 40 + lk * 8];
    }
    #pragma unroll
    for (int mi = 0; mi < 4; ++mi)
      #pragma unroll
      for (int ni = 0; ni < 4; ++ni)
        acc[mi][ni] = __builtin_amdgcn_mfma_f32_16x16x32_bf16(af[mi], bf[ni], acc[mi][ni], 0, 0, 0);
    __syncthreads();
  }

  if (kh == 0) {  // LoRA down extension only once
    for (int i = t; i < 4096; i += 256) {
      const int row = i >> 5, c = i & 31;
      u16 av = 0, bv = 0;
      if (c < TR) {
        av = ha[((size_t)e * TS + m0 + row) * TR + c];
        bv = f2bf(Bd[((size_t)e * TD + n0 + row) * TR + c]);
      }
      lA[row * 40 + c] = av;
      lB[row * 40 + c] = bv;
    }
    __syncthreads();
    short8 af[4], bf[4];
    #pragma unroll
    for (int i = 0; i < 4; ++i) {
      af[i] = *(const short8*)&lA[(wm * 64 + i * 16 + lr) * 40 + lk * 8];
      bf[i] = *(const short8*)&lB[(wn * 64 + i * 16 + lr) * 40 + lk * 8];
    }
    #pragma unroll
    for (int mi = 0; mi < 4; ++mi)
      #pragma unroll
      for (int ni = 0; ni < 4; ++ni)
        acc[mi][ni] = __builtin_amdgcn_mfma_f32_16x16x32_bf16(af[mi], bf[ni], acc[mi][ni], 0, 0, 0);
  }

  // epilogue: out[s,d] += w[s,e] * val
  #pragma unroll
  for (int mi = 0; mi < 4; ++mi)
    #pragma unroll
    for (int j = 0; j < 4; ++j) {
      const int srow = m0 + wm * 64 + mi * 16 + lk * 4 + j;
      const float wgt = wbuf[srow * TE + e];
      if (wgt != 0.f) {
        #pragma unroll
        for (int ni = 0; ni < 4; ++ni) {
          const int dcol = n0 + wn * 64 + ni * 16 + lr;
          unsafeAtomicAdd(&out[(size_t)srow * TD + dcol], wgt * acc[mi][ni][j]);
        }
      }
    }
}

// ================================================================ launch
extern "C" void kernel_launch(void* const* d_in, const int* in_sizes, int n_in,
                              void* d_out, int out_size, void* d_ws, size_t ws_size,
                              hipStream_t stream) {
  const float* x       = (const float*)d_in[0];
  const float* hist    = (const float*)d_in[1];
  const float* persona = (const float*)d_in[2];
  const float* fw1x    = (const float*)d_in[3];
  const float* fw1h    = (const float*)d_in[4];
  const float* fw1p    = (const float*)d_in[5];
  const float* fb1     = (const float*)d_in[6];
  const float* fw2     = (const float*)d_in[7];
  const float* fb2     = (const float*)d_in[8];
  const float* lng     = (const float*)d_in[9];
  const float* lnb     = (const float*)d_in[10];
  const float* gw      = (const float*)d_in[11];
  const float* gb      = (const float*)d_in[12];
  const float* Wg      = (const float*)d_in[13];
  const float* Wu      = (const float*)d_in[14];
  const float* Wd      = (const float*)d_in[15];
  const float* Ag      = (const float*)d_in[16];
  const float* Bg      = (const float*)d_in[17];
  const float* Au      = (const float*)d_in[18];
  const float* Bu      = (const float*)d_in[19];
  const float* Ad      = (const float*)d_in[20];
  const float* Bd      = (const float*)d_in[21];
  float* out = (float*)d_out;

  char* wsb = (char*)d_ws;
  float* hb     = (float*)(wsb + 0);
  float* hp     = (float*)(wsb + 1024);
  float* sc     = (float*)(wsb + 3072);
  float* logits = (float*)(wsb + 4096);
  float* wbuf   = (float*)(wsb + 12288);
  float* h1     = (float*)(wsb + 20480);
  u16*   xbf    = (u16*)(wsb + 282624);
  u16*   xag    = (u16*)(wsb + 3428352);
  u16*   xau    = (u16*)(wsb + 3493888);
  u16*   habf   = (u16*)(wsb + 3559424);
  u16*   hbuf   = (u16*)(wsb + 3624960);
  // total ws usage: 3624960 + 33554432 = 37,179,392 bytes

  k_zero<<<1024, 256, 0, stream>>>(out, out_size);
  k_prep<<<TH1 + 1, 64, 0, stream>>>(hist, fw1h, fb1, persona, fw1p, lng, lnb, gw, hb, hp, sc);
  k_h1<<<TS / 4, 128, 0, stream>>>(x, fw1x, hb, h1);
  k_logits<<<TS, 256, 0, stream>>>(h1, hp, fw2, fb2, lng, lnb, gw, gb, sc, logits);
  k_gate<<<1, TS, 0, stream>>>(logits, wbuf, out + (size_t)TS * TD);
  k_cvtx<<<(TS * TD) / 1024, 256, 0, stream>>>(x, xbf);
  k_xa<<<dim3(TE, TS), 128, 0, stream>>>(x, Ag, Au, xag, xau);
  k_gateup<<<dim3(TF / 128, TS / 128, TE), 256, 0, stream>>>(Wg, Wu, Bg, Bu, xbf, xag, xau, hbuf);
  k_ha<<<dim3(TE, TS), 256, 0, stream>>>(hbuf, Ad, habf);
  k_down<<<dim3(TD / 128, (TS / 128) * 2, TE), 256, 0, stream>>>(Wd, Bd, hbuf, habf, wbuf, out);
}

// Round 2
// 1964.589 us; speedup vs baseline: 1.0754x; 1.0754x over previous
//
#include <hip/hip_runtime.h>

#define TS 512      // seq len (B=1)
#define TD 3072     // llm dim
#define TDH 256     // history dim
#define TE 4        // experts
#define TF 8192     // ffn dim
#define TR 16       // lora rank
#define TH1 128     // fusion hidden

typedef unsigned short u16;
typedef unsigned int u32;

typedef short short8 __attribute__((ext_vector_type(8)));
typedef float f32x4 __attribute__((ext_vector_type(4)));

__device__ __forceinline__ int imin(int a, int b) { return a < b ? a : b; }

__device__ __forceinline__ u16 f2bf(float f) {
  union { float f; u32 u; } v; v.f = f;
  u32 r = v.u + 0x7fffu + ((v.u >> 16) & 1u);   // RNE
  return (u16)(r >> 16);
}
// fast pack: round-half-up + byte-perm (3 VALU insts). a -> low16, b -> high16
__device__ __forceinline__ u32 pk2r(float a, float b) {
  union { float f; u32 u; } x, y; x.f = a; y.f = b;
  return __builtin_amdgcn_perm(y.u + 0x8000u, x.u + 0x8000u, 0x07060302u);
}
__device__ __forceinline__ float bflo(u32 v) {
  union { u32 u; float f; } w; w.u = v << 16; return w.f;
}
__device__ __forceinline__ float bfhi(u32 v) {
  union { u32 u; float f; } w; w.u = v & 0xffff0000u; return w.f;
}
__device__ __forceinline__ float wred(float v) {
  #pragma unroll
  for (int o = 32; o; o >>= 1) v += __shfl_down(v, o);
  return v;
}
__device__ __forceinline__ float dot4(float4 a, float4 b) {
  return a.x*b.x + a.y*b.y + a.z*b.z + a.w*b.w;
}

// ---------------------------------------------------------------- zero out
__global__ void k_zero(float* __restrict__ p, int n) {
  for (int i = blockIdx.x * blockDim.x + threadIdx.x; i < n; i += gridDim.x * blockDim.x)
    p[i] = 0.f;
}

// ---------------------------------------------------------------- gating prep
__global__ void k_prep(const float* __restrict__ hist, const float* __restrict__ fw1h,
                       const float* __restrict__ fb1, const float* __restrict__ persona,
                       const float* __restrict__ fw1p, const float* __restrict__ lng,
                       const float* __restrict__ lnb, const float* __restrict__ gw,
                       float* __restrict__ hb, float* __restrict__ hp, float* __restrict__ sc)
{
  const int k = blockIdx.x, t = threadIdx.x;  // 64 threads
  if (k < TH1) {
    float a = 0.f;
    for (int h = t; h < TDH; h += 64) a += hist[h] * fw1h[k * TDH + h];
    a = wred(a);
    if (t == 0) hb[k] = a + fb1[k];
    for (int e = 0; e < TE; ++e) {
      float b = 0.f;
      for (int d = t; d < TD; d += 64) b += persona[e * TD + d] * fw1p[k * TD + d];
      b = wred(b);
      if (t == 0) hp[e * TH1 + k] = b;
    }
  } else {
    float g = 0.f, bb = 0.f;
    for (int d = t; d < TD; d += 64) { g += lng[d] * gw[d]; bb += lnb[d] * gw[d]; }
    g = wred(g); bb = wred(bb);
    if (t == 0) { sc[0] = g; sc[1] = bb; }
  }
}

// ---------------------------------------------------------------- h1 = x @ fw1x^T + hb
__global__ void k_h1(const float* __restrict__ x, const float* __restrict__ fw1x,
                     const float* __restrict__ hb, float* __restrict__ h1)
{
  const int s0 = blockIdx.x * 4, t = threadIdx.x;
  __shared__ float xr[4][TD];
  for (int r = 0; r < 4; ++r)
    for (int i = t; i < TD / 4; i += 128)
      ((float4*)xr[r])[i] = ((const float4*)(x + (size_t)(s0 + r) * TD))[i];
  __syncthreads();
  float a0 = 0.f, a1 = 0.f, a2 = 0.f, a3 = 0.f;
  const float4* wp = (const float4*)(fw1x + (size_t)t * TD);
  for (int c = 0; c < TD / 4; ++c) {
    float4 wv = wp[c];
    a0 += dot4(wv, ((const float4*)xr[0])[c]);
    a1 += dot4(wv, ((const float4*)xr[1])[c]);
    a2 += dot4(wv, ((const float4*)xr[2])[c]);
    a3 += dot4(wv, ((const float4*)xr[3])[c]);
  }
  const float hv = hb[t];
  h1[(s0 + 0) * TH1 + t] = a0 + hv;
  h1[(s0 + 1) * TH1 + t] = a1 + hv;
  h1[(s0 + 2) * TH1 + t] = a2 + hv;
  h1[(s0 + 3) * TH1 + t] = a3 + hv;
}

// ---------------------------------------------------------------- per-token expert logits
__global__ void k_logits(const float* __restrict__ h1, const float* __restrict__ hp,
                         const float* __restrict__ fw2, const float* __restrict__ fb2,
                         const float* __restrict__ lng, const float* __restrict__ lnb,
                         const float* __restrict__ gw, const float* __restrict__ gbp,
                         const float* __restrict__ sc, float* __restrict__ logits)
{
  const int s = blockIdx.x, t = threadIdx.x;
  __shared__ float h1e[TE][TH1];
  __shared__ float red[4][12];
  if (t < TH1) {
    const float base = h1[s * TH1 + t];
    #pragma unroll
    for (int e = 0; e < TE; ++e) {
      float v = base + hp[e * TH1 + t];
      h1e[e][t] = v > 0.f ? v : 0.f;
    }
  }
  __syncthreads();
  float acc[12][4];
  #pragma unroll
  for (int dd = 0; dd < 12; ++dd)
    #pragma unroll
    for (int e = 0; e < 4; ++e) acc[dd][e] = 0.f;

  for (int c = 0; c < 32; ++c) {
    float4 h4[TE];
    #pragma unroll
    for (int e = 0; e < TE; ++e) h4[e] = *(const float4*)&h1e[e][c * 4];
    #pragma unroll
    for (int dd = 0; dd < 12; ++dd) {
      const int d = t + dd * 256;
      float4 wv = *(const float4*)(fw2 + (size_t)d * TH1 + c * 4);
      #pragma unroll
      for (int e = 0; e < 4; ++e) acc[dd][e] += dot4(wv, h4[e]);
    }
  }
  float s1[4] = {0,0,0,0}, s2[4] = {0,0,0,0}, s3[4] = {0,0,0,0};
  #pragma unroll
  for (int dd = 0; dd < 12; ++dd) {
    const int d = t + dd * 256;
    const float fb = fb2[d];
    const float ggw = lng[d] * gw[d];
    #pragma unroll
    for (int e = 0; e < 4; ++e) {
      float f = acc[dd][e] + fb;
      f = fmaxf(f, 0.f);
      s1[e] += f; s2[e] += f * f; s3[e] += f * ggw;
    }
  }
  #pragma unroll
  for (int e = 0; e < 4; ++e) { s1[e] = wred(s1[e]); s2[e] = wred(s2[e]); s3[e] = wred(s3[e]); }
  const int lane = t & 63, w = t >> 6;
  if (lane == 0) {
    #pragma unroll
    for (int e = 0; e < 4; ++e) { red[w][e] = s1[e]; red[w][4 + e] = s2[e]; red[w][8 + e] = s3[e]; }
  }
  __syncthreads();
  if (t == 0) {
    const float dotg = sc[0], dotb = sc[1], gb = gbp[0];
    #pragma unroll
    for (int e = 0; e < 4; ++e) {
      float S1 = red[0][e] + red[1][e] + red[2][e] + red[3][e];
      float S2 = red[0][4+e] + red[1][4+e] + red[2][4+e] + red[3][4+e];
      float S3 = red[0][8+e] + red[1][8+e] + red[2][8+e] + red[3][8+e];
      float mu = S1 * (1.f / TD);
      float var = S2 * (1.f / TD) - mu * mu;
      float rs = 1.f / sqrtf(var + 1e-5f);
      logits[e * TS + s] = rs * (S3 - mu * dotg) + dotb + gb;
    }
  }
}

// ---------------------------------------------------------------- softmax/top2/entropy + expert token lists
__global__ void k_gate(const float* __restrict__ logits, float* __restrict__ entOut,
                       int* __restrict__ cntg, int* __restrict__ toklist,
                       float* __restrict__ wsel)
{
  const int s = threadIdx.x;  // 512 threads
  __shared__ int cnt[TE];
  if (s < TE) cnt[s] = 0;
  __syncthreads();
  float l[4], p[4];
  #pragma unroll
  for (int e = 0; e < 4; ++e) l[e] = logits[e * TS + s];
  float m = fmaxf(fmaxf(l[0], l[1]), fmaxf(l[2], l[3]));
  float sum = 0.f;
  #pragma unroll
  for (int e = 0; e < 4; ++e) { p[e] = expf(l[e] - m); sum += p[e]; }
  const float inv = 1.f / sum;
  #pragma unroll
  for (int e = 0; e < 4; ++e) p[e] *= inv;
  int i1 = 0; float b1 = p[0];
  #pragma unroll
  for (int e = 1; e < 4; ++e) if (p[e] > b1) { b1 = p[e]; i1 = e; }
  int i2 = -1; float b2 = -1.f;
  #pragma unroll
  for (int e = 0; e < 4; ++e) if (e != i1 && p[e] > b2) { b2 = p[e]; i2 = e; }
  int p1 = atomicAdd(&cnt[i1], 1);
  int p2 = atomicAdd(&cnt[i2], 1);
  toklist[i1 * TS + p1] = s; wsel[i1 * TS + p1] = p[i1];
  toklist[i2 * TS + p2] = s; wsel[i2 * TS + p2] = p[i2];
  float ent = 0.f;
  #pragma unroll
  for (int e = 0; e < 4; ++e) ent -= p[e] * logf(p[e] + 1e-9f);
  ent = wred(ent);
  __shared__ float red[8];
  if ((s & 63) == 0) red[s >> 6] = ent;
  __syncthreads();
  if (s == 0) {
    float tot = 0.f;
    #pragma unroll
    for (int w = 0; w < 8; ++w) tot += red[w];
    entOut[0] = tot * (1.f / TS);
  }
  if (s < TE) cntg[s] = cnt[s];
}

// ---------------------------------------------------------------- x -> bf16
__global__ void k_cvtx(const float* __restrict__ x, u16* __restrict__ xbf) {
  const size_t i = ((size_t)blockIdx.x * 256 + threadIdx.x) * 4;
  float4 v = *(const float4*)(x + i);
  uint2 o; o.x = (u32)f2bf(v.x) | ((u32)f2bf(v.y) << 16);
  o.y = (u32)f2bf(v.z) | ((u32)f2bf(v.w) << 16);
  *(uint2*)(xbf + i) = o;
}

// ---------------------------------------------------------------- xa = x @ A^T (gate & up)
__global__ void k_xa(const float* __restrict__ x, const float* __restrict__ Ag,
                     const float* __restrict__ Au, u16* __restrict__ xag, u16* __restrict__ xau)
{
  const int e = blockIdx.x, s = blockIdx.y, t = threadIdx.x;
  const int wavei = t >> 6, lane = t & 63;
  const int r = lane & 15, q = lane >> 4;
  const float* A = wavei ? Au : Ag;
  u16* dst = wavei ? xau : xag;
  const float4* xv = (const float4*)(x + (size_t)s * TD);
  const float4* av = (const float4*)(A + ((size_t)e * TR + r) * TD);
  float acc = 0.f;
  for (int c = q * 192; c < q * 192 + 192; ++c) acc += dot4(av[c], xv[c]);
  acc += __shfl_xor(acc, 16);
  acc += __shfl_xor(acc, 32);
  if (q == 0) dst[((size_t)e * TS + s) * TR + r] = f2bf(acc);
}

// ---------------------------------------------------------------- fused gate+up GEMM + LoRA + silu
// Gathered tokens per expert; register-prefetch pipeline; perm-based bf16 pack.
// grid (F/128, 4 m-tiles max, E) x 256 thr; blocks with m0>=cnt exit.
__global__ __launch_bounds__(256, 2) void k_gateup(
    const float* __restrict__ Wg, const float* __restrict__ Wu,
    const float* __restrict__ Bg, const float* __restrict__ Bu,
    const u16* __restrict__ xbf, const u16* __restrict__ xag,
    const u16* __restrict__ xau, const int* __restrict__ cntg,
    const int* __restrict__ toklist, u16* __restrict__ hbuf)
{
  __shared__ __attribute__((aligned(16))) u16 lA[128 * 40];
  __shared__ __attribute__((aligned(16))) u16 lBg[128 * 40];
  __shared__ __attribute__((aligned(16))) u16 lBu[128 * 40];
  __shared__ __attribute__((aligned(16))) u16 lA2[128 * 40];
  const int e = blockIdx.z;
  const int cnt = cntg[e];
  const int m0 = blockIdx.y * 128;
  if (m0 >= cnt) return;
  const int n0 = blockIdx.x * 128;
  const int t = threadIdx.x;
  const int lane = t & 63, wv = t >> 6;
  const int wm = wv >> 1, wn = wv & 1;
  const int lr = lane & 15, lk = lane >> 4;
  const int r0 = t >> 2;          // staging row 0..63 (+64 for second half)
  const int cc0 = (t & 3) * 8;    // 8-elem chunk within BK=32

  f32x4 accg[4][4], accu[4][4];
  #pragma unroll
  for (int i = 0; i < 4; ++i)
    #pragma unroll
    for (int j = 0; j < 4; ++j) {
      f32x4 z = {0.f, 0.f, 0.f, 0.f};
      accg[i][j] = z; accu[i][j] = z;
    }

  // gathered token rows for this thread's two staged A rows
  const int tk0 = toklist[e * TS + imin(m0 + r0, cnt - 1)];
  const int tk1 = toklist[e * TS + imin(m0 + r0 + 64, cnt - 1)];
  const u16* a0p = xbf + (size_t)tk0 * TD + cc0;
  const u16* a1p = xbf + (size_t)tk1 * TD + cc0;
  const float* g0p = Wg + ((size_t)e * TF + n0 + r0) * TD + cc0;
  const float* g1p = g0p + (size_t)64 * TD;
  const float* u0p = Wu + ((size_t)e * TF + n0 + r0) * TD + cc0;
  const float* u1p = u0p + (size_t)64 * TD;

  // preload kt=0
  uint4 ra0 = *(const uint4*)a0p;
  uint4 ra1 = *(const uint4*)a1p;
  float4 rg0a = *(const float4*)g0p, rg0b = *(const float4*)(g0p + 4);
  float4 rg1a = *(const float4*)g1p, rg1b = *(const float4*)(g1p + 4);
  float4 ru0a = *(const float4*)u0p, ru0b = *(const float4*)(u0p + 4);
  float4 ru1a = *(const float4*)u1p, ru1b = *(const float4*)(u1p + 4);

  for (int kt = 0; kt < TD; kt += 32) {
    // convert & write stage (from prefetched regs)
    *(uint4*)&lA[r0 * 40 + cc0] = ra0;
    *(uint4*)&lA[(r0 + 64) * 40 + cc0] = ra1;
    uint4 pg0, pg1, pu0, pu1;
    pg0.x = pk2r(rg0a.x, rg0a.y); pg0.y = pk2r(rg0a.z, rg0a.w);
    pg0.z = pk2r(rg0b.x, rg0b.y); pg0.w = pk2r(rg0b.z, rg0b.w);
    pg1.x = pk2r(rg1a.x, rg1a.y); pg1.y = pk2r(rg1a.z, rg1a.w);
    pg1.z = pk2r(rg1b.x, rg1b.y); pg1.w = pk2r(rg1b.z, rg1b.w);
    pu0.x = pk2r(ru0a.x, ru0a.y); pu0.y = pk2r(ru0a.z, ru0a.w);
    pu0.z = pk2r(ru0b.x, ru0b.y); pu0.w = pk2r(ru0b.z, ru0b.w);
    pu1.x = pk2r(ru1a.x, ru1a.y); pu1.y = pk2r(ru1a.z, ru1a.w);
    pu1.z = pk2r(ru1b.x, ru1b.y); pu1.w = pk2r(ru1b.z, ru1b.w);
    *(uint4*)&lBg[r0 * 40 + cc0] = pg0;
    *(uint4*)&lBg[(r0 + 64) * 40 + cc0] = pg1;
    *(uint4*)&lBu[r0 * 40 + cc0] = pu0;
    *(uint4*)&lBu[(r0 + 64) * 40 + cc0] = pu1;
    __syncthreads();
    // issue next iteration's global loads (overlap with MFMA below)
    if (kt + 32 < TD) {
      ra0 = *(const uint4*)(a0p + kt + 32);
      ra1 = *(const uint4*)(a1p + kt + 32);
      rg0a = *(const float4*)(g0p + kt + 32); rg0b = *(const float4*)(g0p + kt + 36);
      rg1a = *(const float4*)(g1p + kt + 32); rg1b = *(const float4*)(g1p + kt + 36);
      ru0a = *(const float4*)(u0p + kt + 32); ru0b = *(const float4*)(u0p + kt + 36);
      ru1a = *(const float4*)(u1p + kt + 32); ru1b = *(const float4*)(u1p + kt + 36);
    }
    short8 af[4], bgf[4], buf[4];
    #pragma unroll
    for (int i = 0; i < 4; ++i) {
      af[i]  = *(const short8*)&lA [(wm * 64 + i * 16 + lr) * 40 + lk * 8];
      bgf[i] = *(const short8*)&lBg[(wn * 64 + i * 16 + lr) * 40 + lk * 8];
      buf[i] = *(const short8*)&lBu[(wn * 64 + i * 16 + lr) * 40 + lk * 8];
    }
    #pragma unroll
    for (int mi = 0; mi < 4; ++mi)
      #pragma unroll
      for (int ni = 0; ni < 4; ++ni) {
        accg[mi][ni] = __builtin_amdgcn_mfma_f32_16x16x32_bf16(af[mi], bgf[ni], accg[mi][ni], 0, 0, 0);
        accu[mi][ni] = __builtin_amdgcn_mfma_f32_16x16x32_bf16(af[mi], buf[ni], accu[mi][ni], 0, 0, 0);
      }
    __syncthreads();
  }

  // LoRA rank-16 extension step (K padded to 32 with zeros), gathered by token
  for (int i = t; i < 4096; i += 256) {
    const int row = i >> 5, c = i & 31;
    u16 vag = 0, vau = 0, vbg = 0, vbu = 0;
    if (c < TR) {
      const int tkr = toklist[e * TS + imin(m0 + row, cnt - 1)];
      vag = xag[((size_t)e * TS + tkr) * TR + c];
      vau = xau[((size_t)e * TS + tkr) * TR + c];
      vbg = f2bf(Bg[((size_t)e * TF + n0 + row) * TR + c]);
      vbu = f2bf(Bu[((size_t)e * TF + n0 + row) * TR + c]);
    }
    lA [row * 40 + c] = vag;
    lA2[row * 40 + c] = vau;
    lBg[row * 40 + c] = vbg;
    lBu[row * 40 + c] = vbu;
  }
  __syncthreads();
  {
    short8 ag[4], au[4], bgf[4], buf[4];
    #pragma unroll
    for (int i = 0; i < 4; ++i) {
      ag[i]  = *(const short8*)&lA [(wm * 64 + i * 16 + lr) * 40 + lk * 8];
      au[i]  = *(const short8*)&lA2[(wm * 64 + i * 16 + lr) * 40 + lk * 8];
      bgf[i] = *(const short8*)&lBg[(wn * 64 + i * 16 + lr) * 40 + lk * 8];
      buf[i] = *(const short8*)&lBu[(wn * 64 + i * 16 + lr) * 40 + lk * 8];
    }
    #pragma unroll
    for (int mi = 0; mi < 4; ++mi)
      #pragma unroll
      for (int ni = 0; ni < 4; ++ni) {
        accg[mi][ni] = __builtin_amdgcn_mfma_f32_16x16x32_bf16(ag[mi], bgf[ni], accg[mi][ni], 0, 0, 0);
        accu[mi][ni] = __builtin_amdgcn_mfma_f32_16x16x32_bf16(au[mi], buf[ni], accu[mi][ni], 0, 0, 0);
      }
  }

  // epilogue: h = silu(g) * u -> bf16, stored by (expert, pair-slot)
  u16* hrow = hbuf + ((size_t)e * TS + m0) * TF + n0;
  #pragma unroll
  for (int mi = 0; mi < 4; ++mi)
    #pragma unroll
    for (int j = 0; j < 4; ++j) {
      const int srow = wm * 64 + mi * 16 + lk * 4 + j;
      #pragma unroll
      for (int ni = 0; ni < 4; ++ni) {
        const int fcol = wn * 64 + ni * 16 + lr;
        float g = accg[mi][ni][j];
        float u = accu[mi][ni][j];
        float hval = (g / (1.f + __expf(-g))) * u;
        hrow[(size_t)srow * TF + fcol] = f2bf(hval);
      }
    }
}

// ---------------------------------------------------------------- ha = h @ Adown^T per (expert,pair)
__global__ void k_ha(const u16* __restrict__ hbuf, const float* __restrict__ Ad,
                     const int* __restrict__ cntg, u16* __restrict__ ha)
{
  const int e = blockIdx.x, i = blockIdx.y, t = threadIdx.x;
  if (i >= cntg[e]) return;
  const int wv = t >> 6, lane = t & 63;
  const int r = lane & 15, seg = (lane >> 4) + (wv << 2);  // 0..15, 512 f each
  const u16* hrow = hbuf + ((size_t)e * TS + i) * TF + seg * 512;
  const float* arow = Ad + ((size_t)e * TR + r) * TF + seg * 512;
  float acc = 0.f;
  for (int c = 0; c < 512; c += 4) {
    uint2 hv = *(const uint2*)(hrow + c);
    float4 av = *(const float4*)(arow + c);
    acc += bflo(hv.x) * av.x + bfhi(hv.x) * av.y + bflo(hv.y) * av.z + bfhi(hv.y) * av.w;
  }
  acc += __shfl_xor(acc, 16);
  acc += __shfl_xor(acc, 32);
  __shared__ float red[4][16];
  if ((lane >> 4) == 0) red[wv][r] = acc;
  __syncthreads();
  if (wv == 0 && lane < 16) {
    float tot = red[0][lane] + red[1][lane] + red[2][lane] + red[3][lane];
    ha[((size_t)e * TS + i) * TR + lane] = f2bf(tot);
  }
}

// ---------------------------------------------------------------- down GEMM + LoRA + weighted scatter
// grid (D/128, 4 m-tiles x 4 splitK, E) x 256 thr; gathered pairs; atomics into out
__global__ __launch_bounds__(256, 2) void k_down(
    const float* __restrict__ Wd, const float* __restrict__ Bd,
    const u16* __restrict__ hbuf, const u16* __restrict__ ha,
    const int* __restrict__ cntg, const int* __restrict__ toklist,
    const float* __restrict__ wsel, float* __restrict__ out)
{
  __shared__ __attribute__((aligned(16))) u16 lA[128 * 40];
  __shared__ __attribute__((aligned(16))) u16 lB[128 * 40];
  const int e = blockIdx.z;
  const int cnt = cntg[e];
  const int m0 = (blockIdx.y >> 2) * 128;
  if (m0 >= cnt) return;
  const int kh = blockIdx.y & 3;               // K quarter (2048 each)
  const int n0 = blockIdx.x * 128;
  const int t = threadIdx.x;
  const int lane = t & 63, wv = t >> 6;
  const int wm = wv >> 1, wn = wv & 1;
  const int lr = lane & 15, lk = lane >> 4;
  const int r0 = t >> 2, cc0 = (t & 3) * 8;

  f32x4 acc[4][4];
  #pragma unroll
  for (int i = 0; i < 4; ++i)
    #pragma unroll
    for (int j = 0; j < 4; ++j) { f32x4 z = {0.f, 0.f, 0.f, 0.f}; acc[i][j] = z; }

  const int iA0 = imin(m0 + r0, cnt - 1);
  const int iA1 = imin(m0 + r0 + 64, cnt - 1);
  const u16* a0p = hbuf + ((size_t)e * TS + iA0) * TF + cc0;
  const u16* a1p = hbuf + ((size_t)e * TS + iA1) * TF + cc0;
  const float* w0p = Wd + ((size_t)e * TD + n0 + r0) * TF + cc0;
  const float* w1p = w0p + (size_t)64 * TF;

  const int k0 = kh * 2048;
  uint4 ra0 = *(const uint4*)(a0p + k0);
  uint4 ra1 = *(const uint4*)(a1p + k0);
  float4 rw0a = *(const float4*)(w0p + k0), rw0b = *(const float4*)(w0p + k0 + 4);
  float4 rw1a = *(const float4*)(w1p + k0), rw1b = *(const float4*)(w1p + k0 + 4);

  for (int kt = k0; kt < k0 + 2048; kt += 32) {
    *(uint4*)&lA[r0 * 40 + cc0] = ra0;
    *(uint4*)&lA[(r0 + 64) * 40 + cc0] = ra1;
    uint4 p0, p1;
    p0.x = pk2r(rw0a.x, rw0a.y); p0.y = pk2r(rw0a.z, rw0a.w);
    p0.z = pk2r(rw0b.x, rw0b.y); p0.w = pk2r(rw0b.z, rw0b.w);
    p1.x = pk2r(rw1a.x, rw1a.y); p1.y = pk2r(rw1a.z, rw1a.w);
    p1.z = pk2r(rw1b.x, rw1b.y); p1.w = pk2r(rw1b.z, rw1b.w);
    *(uint4*)&lB[r0 * 40 + cc0] = p0;
    *(uint4*)&lB[(r0 + 64) * 40 + cc0] = p1;
    __syncthreads();
    if (kt + 32 < k0 + 2048) {
      ra0 = *(const uint4*)(a0p + kt + 32);
      ra1 = *(const uint4*)(a1p + kt + 32);
      rw0a = *(const float4*)(w0p + kt + 32); rw0b = *(const float4*)(w0p + kt + 36);
      rw1a = *(const float4*)(w1p + kt + 32); rw1b = *(const float4*)(w1p + kt + 36);
    }
    short8 af[4], bf[4];
    #pragma unroll
    for (int i = 0; i < 4; ++i) {
      af[i] = *(const short8*)&lA[(wm * 64 + i * 16 + lr) * 40 + lk * 8];
      bf[i] = *(const short8*)&lB[(wn * 64 + i * 16 + lr) * 40 + lk * 8];
    }
    #pragma unroll
    for (int mi = 0; mi < 4; ++mi)
      #pragma unroll
      for (int ni = 0; ni < 4; ++ni)
        acc[mi][ni] = __builtin_amdgcn_mfma_f32_16x16x32_bf16(af[mi], bf[ni], acc[mi][ni], 0, 0, 0);
    __syncthreads();
  }

  if (kh == 0) {  // LoRA down extension only once
    for (int i = t; i < 4096; i += 256) {
      const int row = i >> 5, c = i & 31;
      u16 av = 0, bv = 0;
      if (c < TR) {
        const int ii = imin(m0 + row, cnt - 1);
        av = ha[((size_t)e * TS + ii) * TR + c];
        bv = f2bf(Bd[((size_t)e * TD + n0 + row) * TR + c]);
      }
      lA[row * 40 + c] = av;
      lB[row * 40 + c] = bv;
    }
    __syncthreads();
    short8 af[4], bf[4];
    #pragma unroll
    for (int i = 0; i < 4; ++i) {
      af[i] = *(const short8*)&lA[(wm * 64 + i * 16 + lr) * 40 + lk * 8];
      bf[i] = *(const short8*)&lB[(wn * 64 + i * 16 + lr) * 40 + lk * 8];
    }
    #pragma unroll
    for (int mi = 0; mi < 4; ++mi)
      #pragma unroll
      for (int ni = 0; ni < 4; ++ni)
        acc[mi][ni] = __builtin_amdgcn_mfma_f32_16x16x32_bf16(af[mi], bf[ni], acc[mi][ni], 0, 0, 0);
  }

  // epilogue: out[tok,d] += w * val (only valid pairs)
  #pragma unroll
  for (int mi = 0; mi < 4; ++mi)
    #pragma unroll
    for (int j = 0; j < 4; ++j) {
      const int srow = wm * 64 + mi * 16 + lk * 4 + j;
      const int ip = m0 + srow;
      if (ip < cnt) {
        const int tok = toklist[e * TS + ip];
        const float wgt = wsel[e * TS + ip];
        #pragma unroll
        for (int ni = 0; ni < 4; ++ni) {
          const int dcol = n0 + wn * 64 + ni * 16 + lr;
          unsafeAtomicAdd(&out[(size_t)tok * TD + dcol], wgt * acc[mi][ni][j]);
        }
      }
    }
}

// ================================================================ launch
extern "C" void kernel_launch(void* const* d_in, const int* in_sizes, int n_in,
                              void* d_out, int out_size, void* d_ws, size_t ws_size,
                              hipStream_t stream) {
  const float* x       = (const float*)d_in[0];
  const float* hist    = (const float*)d_in[1];
  const float* persona = (const float*)d_in[2];
  const float* fw1x    = (const float*)d_in[3];
  const float* fw1h    = (const float*)d_in[4];
  const float* fw1p    = (const float*)d_in[5];
  const float* fb1     = (const float*)d_in[6];
  const float* fw2     = (const float*)d_in[7];
  const float* fb2     = (const float*)d_in[8];
  const float* lng     = (const float*)d_in[9];
  const float* lnb     = (const float*)d_in[10];
  const float* gw      = (const float*)d_in[11];
  const float* gb      = (const float*)d_in[12];
  const float* Wg      = (const float*)d_in[13];
  const float* Wu      = (const float*)d_in[14];
  const float* Wd      = (const float*)d_in[15];
  const float* Ag      = (const float*)d_in[16];
  const float* Bg      = (const float*)d_in[17];
  const float* Au      = (const float*)d_in[18];
  const float* Bu      = (const float*)d_in[19];
  const float* Ad      = (const float*)d_in[20];
  const float* Bd      = (const float*)d_in[21];
  float* out = (float*)d_out;

  char* wsb = (char*)d_ws;
  float* hb      = (float*)(wsb + 0);         // 512 B
  float* hp      = (float*)(wsb + 1024);      // 2 KB
  float* sc      = (float*)(wsb + 3072);      // 8 B
  float* logits  = (float*)(wsb + 4096);      // 8 KB
  int*   cntg    = (int*)  (wsb + 12288);     // 16 B
  int*   toklist = (int*)  (wsb + 16384);     // 8 KB
  float* wsel    = (float*)(wsb + 24576);     // 8 KB
  float* h1      = (float*)(wsb + 32768);     // 256 KB
  u16*   xbf     = (u16*)  (wsb + 294912);    // 3 MB
  u16*   xag     = (u16*)  (wsb + 3440640);   // 64 KB
  u16*   xau     = (u16*)  (wsb + 3506176);   // 64 KB
  u16*   habf    = (u16*)  (wsb + 3571712);   // 64 KB
  u16*   hbuf    = (u16*)  (wsb + 3637248);   // 33.5 MB -> total ~37.2 MB

  k_zero<<<1024, 256, 0, stream>>>(out, out_size);
  k_prep<<<TH1 + 1, 64, 0, stream>>>(hist, fw1h, fb1, persona, fw1p, lng, lnb, gw, hb, hp, sc);
  k_h1<<<TS / 4, 128, 0, stream>>>(x, fw1x, hb, h1);
  k_logits<<<TS, 256, 0, stream>>>(h1, hp, fw2, fb2, lng, lnb, gw, gb, sc, logits);
  k_gate<<<1, TS, 0, stream>>>(logits, out + (size_t)TS * TD, cntg, toklist, wsel);
  k_cvtx<<<(TS * TD) / 1024, 256, 0, stream>>>(x, xbf);
  k_xa<<<dim3(TE, TS), 128, 0, stream>>>(x, Ag, Au, xag, xau);
  k_gateup<<<dim3(TF / 128, TS / 128, TE), 256, 0, stream>>>(Wg, Wu, Bg, Bu, xbf, xag, xau, cntg, toklist, hbuf);
  k_ha<<<dim3(TE, TS), 256, 0, stream>>>(hbuf, Ad, cntg, habf);
  k_down<<<dim3(TD / 128, 16, TE), 256, 0, stream>>>(Wd, Bd, hbuf, habf, cntg, toklist, wsel, out);
}